// Round 4
// baseline (270.666 us; speedup 1.0000x reference)
//
#include <hip/hip_runtime.h>
#include <hip/hip_bf16.h>

typedef __attribute__((ext_vector_type(8))) short bf16x8;
typedef __attribute__((ext_vector_type(4))) float f32x4;

// round-to-nearest-even float -> bf16 bits (host-prep path)
static __device__ __forceinline__ short f2bf(float x) {
    union { float f; unsigned u; } v; v.f = x;
    unsigned r = v.u + 0x7FFFu + ((v.u >> 16) & 1u);
    return (short)(r >> 16);
}

// packed RNE f32x2 -> bf16x2 (hardware)
static __device__ __forceinline__ unsigned cvt_pk_bf16(float lo, float hi) {
    unsigned r;
    asm("v_cvt_pk_bf16_f32 %0, %1, %2" : "=v"(r) : "v"(lo), "v"(hi));
    return r;
}

// W1 [K=256][N=256] fp32 -> W1T [N=256][K=256] bf16
__global__ void prep_w1t(const float* __restrict__ W1, short* __restrict__ W1T) {
    int t = blockIdx.x * 256 + threadIdx.x;
    int n = t >> 8, k = t & 255;
    W1T[t] = f2bf(W1[k * 256 + n]);
}

// One block = one 128-row tile. 512 threads = 8 waves. 2 col-passes of 128.
// Swapped-operand MFMA: D's lane&15 dim = pair row, (g,reg) dim = W1 col.
__global__ __launch_bounds__(512, 4)
void pair_mlp(const int* __restrict__ pidx, const int* __restrict__ qidx,
              const float* __restrict__ emb, const short* __restrict__ w1t,
              const float* __restrict__ b1, const float* __restrict__ w2,
              const float* __restrict__ b2p, float* __restrict__ out, int M)
{
    __shared__ short At[128 * 256];   // 64 KB bf16 A-tile (full K)
    __shared__ float Red[8 * 128];    // 4 KB cross-wave reduction

    const int tid  = threadIdx.x;
    const int lane = tid & 63;
    const int wv   = tid >> 6;        // wave 0..7
    const int c    = lane & 15;
    const int g    = lane >> 4;
    const int base = blockIdx.x * 128;

    // ---- conv phase: gather rows, diff^2 -> bf16 -> LDS (8 K=32 sub-steps) ----
    const int r  = tid >> 2;          // tile row 0..127
    const int sg = tid & 3;           // 8-float segment within K=32
    {
        int im = base + r; im = im < M ? im : M - 1;
        const float* pp = emb + (size_t)pidx[im] * 256;
        const float* qp = emb + (size_t)qidx[im] * 256;

        float4 P0, P1, Q0, Q1, nP0, nP1, nQ0, nQ1;
        {
            const float* ps = pp + sg * 8;
            const float* qs = qp + sg * 8;
            P0 = ((const float4*)ps)[0]; P1 = ((const float4*)ps)[1];
            Q0 = ((const float4*)qs)[0]; Q1 = ((const float4*)qs)[1];
        }
#pragma unroll
        for (int s = 0; s < 8; ++s) {
            if (s < 7) {
                const float* ps = pp + (s + 1) * 32 + sg * 8;
                const float* qs = qp + (s + 1) * 32 + sg * 8;
                nP0 = ((const float4*)ps)[0]; nP1 = ((const float4*)ps)[1];
                nQ0 = ((const float4*)qs)[0]; nQ1 = ((const float4*)qs)[1];
            }
            float d0 = P0.x - Q0.x, d1 = P0.y - Q0.y;
            float d2 = P0.z - Q0.z, d3 = P0.w - Q0.w;
            float d4 = P1.x - Q1.x, d5 = P1.y - Q1.y;
            float d6 = P1.z - Q1.z, d7 = P1.w - Q1.w;
            union { bf16x8 v; unsigned u[4]; } a;
            a.u[0] = cvt_pk_bf16(d0 * d0, d1 * d1);
            a.u[1] = cvt_pk_bf16(d2 * d2, d3 * d3);
            a.u[2] = cvt_pk_bf16(d4 * d4, d5 * d5);
            a.u[3] = cvt_pk_bf16(d6 * d6, d7 * d7);
            int chunk = (s * 4 + sg) ^ (r & 7);       // XOR swizzle, bijective
            *(bf16x8*)(At + r * 256 + chunk * 8) = a.v;
            P0 = nP0; P1 = nP1; Q0 = nQ0; Q1 = nQ1;
        }
    }
    __syncthreads();

    // ---- 2 col-passes of MFMA + relu-dot epilogue ----
    float part[8];
#pragma unroll
    for (int m = 0; m < 8; ++m) part[m] = 0.f;

#pragma unroll
    for (int pass = 0; pass < 2; ++pass) {
        const int colbase = pass * 128 + wv * 16;

        bf16x8 bfr[8];
#pragma unroll
        for (int kc = 0; kc < 8; ++kc)
            bfr[kc] = *(const bf16x8*)(w1t + (colbase + c) * 256 + kc * 32 + g * 8);

        float b1v[4], w2v[4];
#pragma unroll
        for (int j = 0; j < 4; ++j) {
            b1v[j] = b1[colbase + g * 4 + j];
            w2v[j] = w2[colbase + g * 4 + j];
        }

        f32x4 acc[8];
#pragma unroll
        for (int m = 0; m < 8; ++m) acc[m] = (f32x4)0.0f;

#pragma unroll
        for (int kc = 0; kc < 8; ++kc) {
#pragma unroll
            for (int m = 0; m < 8; ++m) {
                bf16x8 a = *(const bf16x8*)(At + (m * 16 + c) * 256 +
                                            (((kc * 4 + g) ^ (c & 7)) * 8));
                // swapped operands: first = W1T frag, second = A frag
                acc[m] = __builtin_amdgcn_mfma_f32_16x16x32_bf16(
                    bfr[kc], a, acc[m], 0, 0, 0);
            }
        }

        // lane(c,g) reg j holds h[row m*16+c][col colbase + g*4 + j]
#pragma unroll
        for (int m = 0; m < 8; ++m) {
#pragma unroll
            for (int j = 0; j < 4; ++j) {
                float h = acc[m][j] + b1v[j];
                h = h > 0.f ? h : 0.f;
                part[m] += h * w2v[j];
            }
        }
    }

    // reduce over g (lanes 16/32 apart); c-lanes then hold per-row sums
#pragma unroll
    for (int m = 0; m < 8; ++m) {
        part[m] += __shfl_xor(part[m], 16, 64);
        part[m] += __shfl_xor(part[m], 32, 64);
    }
    if (g == 0) {
#pragma unroll
        for (int m = 0; m < 8; ++m) Red[wv * 128 + m * 16 + c] = part[m];
    }
    __syncthreads();

    if (tid < 128) {
        int row = base + tid;
        if (row < M) {
            float s = b2p[0];
#pragma unroll
            for (int w = 0; w < 8; ++w) s += Red[w * 128 + tid];
            out[row] = s;
        }
    }
}

extern "C" void kernel_launch(void* const* d_in, const int* in_sizes, int n_in,
                              void* d_out, int out_size, void* d_ws, size_t ws_size,
                              hipStream_t stream) {
    const int*   p   = (const int*)d_in[0];
    const int*   q   = (const int*)d_in[1];
    const float* emb = (const float*)d_in[2];
    const float* W1  = (const float*)d_in[3];
    const float* b1  = (const float*)d_in[4];
    const float* W2  = (const float*)d_in[5];
    const float* b2  = (const float*)d_in[6];
    float* out = (float*)d_out;
    short* w1t = (short*)d_ws;          // 128 KB scratch
    int M = in_sizes[0];
    int NT = (M + 127) / 128;

    prep_w1t<<<256, 256, 0, stream>>>(W1, w1t);
    pair_mlp<<<NT, 512, 0, stream>>>(p, q, emb, w1t, b1, W2, b2, out, M);
}